// Round 1
// baseline (478.788 us; speedup 1.0000x reference)
//
#include <hip/hip_runtime.h>
#include <math.h>

// ---------------------------------------------------------------------------
// LinearAttention: out = ((x@Wqkv -> q,k,v; k=softmax_T(k); k[mask]=0;
//                          ctx=k^T v per (b,h); (q*s)@ctx) reshaped) @ Wout + b
// Folded as: qs = q*scale (bf16), M2[b] = blockdiag_h(ctx[b,h]/sumexp) @ Wout,
//            out = qs[b] @ M2[b] + b_out.
// B=4 T=4096 DIM=1024 H=16 Dh=64, 3*INNER=3072.
// ---------------------------------------------------------------------------

typedef __bf16 bf16;
typedef __attribute__((ext_vector_type(4))) float f32x4;
typedef __attribute__((ext_vector_type(8))) __bf16 bf16x8;
typedef __attribute__((ext_vector_type(4))) __bf16 bf16x4;

#define SCALE_ 0.125f   // 64^-0.5

__device__ __forceinline__ void g2l16(const void* g, void* l) {
  __builtin_amdgcn_global_load_lds((const __attribute__((address_space(1))) void*)g,
                                   (__attribute__((address_space(3))) void*)l, 16, 0, 0);
}

// ---- x (fp32) -> bf16, vectorized ----------------------------------------
__global__ __launch_bounds__(256) void k_cvt(const float* __restrict__ in,
                                             bf16* __restrict__ out, int n4) {
  int i = blockIdx.x * 256 + threadIdx.x;
  if (i >= n4) return;
  f32x4 v = ((const f32x4*)in)[i];
  bf16x4 o;
  o[0] = (bf16)v[0]; o[1] = (bf16)v[1]; o[2] = (bf16)v[2]; o[3] = (bf16)v[3];
  ((bf16x4*)out)[i] = o;
}

// ---- W_qkv [1024][3072] fp32 -> Wt [3072][1024] bf16 (tiled transpose) ----
__global__ __launch_bounds__(256) void k_trans(const float* __restrict__ W,
                                               bf16* __restrict__ Wt) {
  __shared__ float t[32][33];
  int n0 = blockIdx.x * 32, k0 = blockIdx.y * 32;
  int tx = threadIdx.x & 31, ty = threadIdx.x >> 5;
  #pragma unroll
  for (int s = 0; s < 4; s++) {
    int k = ty + s * 8;
    t[k][tx] = W[(size_t)(k0 + k) * 3072 + n0 + tx];
  }
  __syncthreads();
  #pragma unroll
  for (int s = 0; s < 4; s++) {
    int n = ty + s * 8;
    Wt[(size_t)(n0 + n) * 1024 + k0 + tx] = (bf16)t[tx][n];
  }
}

// ---- GEMM1: [16384,1024] @ Wt^T -> qkv. Epilogue: q*scale->qs bf16, kv bf16.
// m97 structure: 128x128 tile, BK=32, 4 waves (2x2), 16x16x32 MFMA,
// global_load_lds width=16 staging.
__global__ __launch_bounds__(256) void k_gemm1(const bf16* __restrict__ A,
                                               const bf16* __restrict__ Bt,
                                               bf16* __restrict__ qs,
                                               bf16* __restrict__ kv) {
  __shared__ __align__(16) bf16 As[128 * 32];
  __shared__ __align__(16) bf16 Bs[128 * 32];
  const int tid = threadIdx.x;
  const int wave = tid >> 6, lane = tid & 63, l16 = lane & 15, quad = lane >> 4;
  const int wm = (wave >> 1) << 6, wn = (wave & 1) << 6;
  const int row0 = blockIdx.y << 7, col0 = blockIdx.x << 7;
  f32x4 acc[4][4] = {};
  for (int kt = 0; kt < 1024; kt += 32) {
    #pragma unroll
    for (int it = 0; it < 2; ++it) {
      const int cb = (wave * 2 + it) * 64;
      const int c = cb + lane;
      const int m = c >> 2, k8 = (c & 3) * 8;
      g2l16(A  + (size_t)(row0 + m) * 1024 + kt + k8, As + cb * 8);
      g2l16(Bt + (size_t)(col0 + m) * 1024 + kt + k8, Bs + cb * 8);
    }
    __syncthreads();
    bf16x8 af[4], bfr[4];
    #pragma unroll
    for (int i = 0; i < 4; i++) af[i]  = *(const bf16x8*)(As + (wm + i * 16 + l16) * 32 + quad * 8);
    #pragma unroll
    for (int j = 0; j < 4; j++) bfr[j] = *(const bf16x8*)(Bs + (wn + j * 16 + l16) * 32 + quad * 8);
    #pragma unroll
    for (int i = 0; i < 4; i++)
      #pragma unroll
      for (int j = 0; j < 4; j++)
        acc[i][j] = __builtin_amdgcn_mfma_f32_16x16x32_bf16(af[i], bfr[j], acc[i][j], 0, 0, 0);
    __syncthreads();
  }
  // C/D layout: col = lane&15, row = (lane>>4)*4 + reg  [m89-verified]
  #pragma unroll
  for (int i = 0; i < 4; i++) {
    const int gm0 = row0 + wm + i * 16 + quad * 4;
    #pragma unroll
    for (int j = 0; j < 4; j++) {
      const int gc = col0 + wn + j * 16 + l16;
      #pragma unroll
      for (int r = 0; r < 4; r++) {
        const float v = acc[i][j][r];
        const size_t row = (size_t)(gm0 + r);
        if (gc < 1024) qs[row * 1024 + gc] = (bf16)(v * SCALE_);
        else           kv[row * 2048 + (gc - 1024)] = (bf16)v;
      }
    }
  }
}

// ---- column sumexp over n for k: sumexp[b*1024+d] = sum_n exp(k[b,n,d]) ----
// k ~ N(0,1): no max-subtraction needed (exp < ~300, sum < ~1e6).
__global__ __launch_bounds__(256) void k_stats(const bf16* __restrict__ kv,
                                               float* __restrict__ sumexp) {
  const int b = blockIdx.z;
  const int d = blockIdx.y * 256 + threadIdx.x;
  const int n0 = blockIdx.x * 256;
  const bf16* p = kv + ((size_t)(b * 4096 + n0)) * 2048 + d;
  float s = 0.f;
  #pragma unroll 8
  for (int i = 0; i < 256; i++) s += __expf((float)p[(size_t)i * 2048]);
  atomicAdd(&sumexp[b * 1024 + d], s);
}

// ---- ctxraw[b,h,d,e] = sum_{n unmasked} exp(k[n,hd]) * v[n,he] -------------
// grid (nsplit=8, H=16, B=4); 8x8 register outer product per lane; 4 waves
// duplicate (d,e) over disjoint n; LDS pairwise reduce then global atomicAdd.
__global__ __launch_bounds__(256) void k_ctx(const bf16* __restrict__ kv,
                                             const int* __restrict__ mask,
                                             float* __restrict__ ctx) {
  __shared__ float Lk[64][64];
  __shared__ float Lv[64][64];
  const int b = blockIdx.z, h = blockIdx.y, ns = blockIdx.x;
  const int tid = threadIdx.x, wave = tid >> 6, lane = tid & 63;
  const int d0 = (lane & 7) * 8, e0 = (lane >> 3) * 8;
  float acc[8][8] = {};
  const int nbase = ns * 512;
  for (int ch = 0; ch < 8; ++ch) {
    const int n0 = nbase + ch * 64;
    __syncthreads();
    for (int idx = tid; idx < 4096; idx += 256) {
      const int nl = idx >> 6, cc = idx & 63;
      const size_t rbase = (size_t)(b * 4096 + n0 + nl) * 2048 + h * 64;
      const int mk = mask[b * 4096 + n0 + nl];
      Lk[nl][cc] = mk ? 0.f : __expf((float)kv[rbase + cc]);
      Lv[nl][cc] = (float)kv[rbase + 1024 + cc];
    }
    __syncthreads();
    #pragma unroll 4
    for (int t = 0; t < 16; t++) {
      const int n = (wave << 4) + t;
      f32x4 ka = *(const f32x4*)&Lk[n][d0];
      f32x4 kb = *(const f32x4*)&Lk[n][d0 + 4];
      f32x4 va = *(const f32x4*)&Lv[n][e0];
      f32x4 vb = *(const f32x4*)&Lv[n][e0 + 4];
      float kk[8] = {ka[0], ka[1], ka[2], ka[3], kb[0], kb[1], kb[2], kb[3]};
      float vv[8] = {va[0], va[1], va[2], va[3], vb[0], vb[1], vb[2], vb[3]};
      #pragma unroll
      for (int a = 0; a < 8; a++)
        #pragma unroll
        for (int c = 0; c < 8; c++) acc[a][c] += kk[a] * vv[c];
    }
  }
  __syncthreads();
  float* r0 = &Lk[0][0];
  float* r1 = &Lv[0][0];
  if (wave < 2) {
    float* r = wave ? r1 : r0;
    #pragma unroll
    for (int a = 0; a < 8; a++)
      #pragma unroll
      for (int c = 0; c < 8; c++) r[(d0 + a) * 64 + e0 + c] = acc[a][c];
  }
  __syncthreads();
  if (wave >= 2) {
    float* r = (wave == 3) ? r1 : r0;
    #pragma unroll
    for (int a = 0; a < 8; a++)
      #pragma unroll
      for (int c = 0; c < 8; c++) r[(d0 + a) * 64 + e0 + c] += acc[a][c];
  }
  __syncthreads();
  float* cbase = ctx + ((size_t)(b * 16 + h) << 12);
  for (int i = tid; i < 4096; i += 256) atomicAdd(cbase + i, r0[i] + r1[i]);
}

// ---- M2t[b][j][h*64+d] = (1/sumexp[b,hd]) * sum_e ctx[b,h,d,e]*Wout[he][j] -
__global__ __launch_bounds__(256) void k_m2(const float* __restrict__ ctx,
                                            const float* __restrict__ sumexp,
                                            const float* __restrict__ Wout,
                                            bf16* __restrict__ M2t) {
  __shared__ float Lc[64][64];
  __shared__ float Linv[64];
  const int b = blockIdx.z, h = blockIdx.y, jt = blockIdx.x;
  const int tid = threadIdx.x, dg = tid >> 6, jl = tid & 63;
  const float* cbase = ctx + ((size_t)(b * 16 + h) << 12);
  for (int i = tid; i < 4096; i += 256) (&Lc[0][0])[i] = cbase[i];
  if (tid < 64) Linv[tid] = 1.f / sumexp[b * 1024 + h * 64 + tid];
  __syncthreads();
  float acc[4][16] = {};
  const int j0 = jt * 256 + jl;
  for (int e = 0; e < 64; e++) {
    const float* wrow = Wout + (size_t)(h * 64 + e) * 1024 + j0;
    float w0 = wrow[0], w1 = wrow[64], w2 = wrow[128], w3 = wrow[192];
    #pragma unroll
    for (int dd = 0; dd < 16; dd++) {
      float c = Lc[dg * 16 + dd][e];  // wave-uniform -> LDS broadcast
      acc[0][dd] += c * w0; acc[1][dd] += c * w1;
      acc[2][dd] += c * w2; acc[3][dd] += c * w3;
    }
  }
  #pragma unroll
  for (int jj = 0; jj < 4; jj++) {
    const size_t jrow = ((size_t)b << 20) + (size_t)(jt * 256 + jl + jj * 64) * 1024 + h * 64 + dg * 16;
    #pragma unroll
    for (int dd = 0; dd < 16; dd++)
      M2t[jrow + dd] = (bf16)(acc[jj][dd] * Linv[dg * 16 + dd]);
  }
}

// ---- GEMM2: out[b] = qs[b] @ M2t[b]^T + b_out, fp32 out -------------------
__global__ __launch_bounds__(256) void k_gemm2(const bf16* __restrict__ A,
                                               const bf16* __restrict__ M2t,
                                               const float* __restrict__ bias,
                                               float* __restrict__ out) {
  __shared__ __align__(16) bf16 As[128 * 32];
  __shared__ __align__(16) bf16 Bs[128 * 32];
  const int tid = threadIdx.x;
  const int wave = tid >> 6, lane = tid & 63, l16 = lane & 15, quad = lane >> 4;
  const int wm = (wave >> 1) << 6, wn = (wave & 1) << 6;
  const int row0 = blockIdx.y << 7, col0 = blockIdx.x << 7;
  const bf16* Bt = M2t + ((size_t)(row0 >> 12) << 20);  // per-batch M2
  f32x4 acc[4][4] = {};
  for (int kt = 0; kt < 1024; kt += 32) {
    #pragma unroll
    for (int it = 0; it < 2; ++it) {
      const int cb = (wave * 2 + it) * 64;
      const int c = cb + lane;
      const int m = c >> 2, k8 = (c & 3) * 8;
      g2l16(A  + (size_t)(row0 + m) * 1024 + kt + k8, As + cb * 8);
      g2l16(Bt + (size_t)(col0 + m) * 1024 + kt + k8, Bs + cb * 8);
    }
    __syncthreads();
    bf16x8 af[4], bfr[4];
    #pragma unroll
    for (int i = 0; i < 4; i++) af[i]  = *(const bf16x8*)(As + (wm + i * 16 + l16) * 32 + quad * 8);
    #pragma unroll
    for (int j = 0; j < 4; j++) bfr[j] = *(const bf16x8*)(Bs + (wn + j * 16 + l16) * 32 + quad * 8);
    #pragma unroll
    for (int i = 0; i < 4; i++)
      #pragma unroll
      for (int j = 0; j < 4; j++)
        acc[i][j] = __builtin_amdgcn_mfma_f32_16x16x32_bf16(af[i], bfr[j], acc[i][j], 0, 0, 0);
    __syncthreads();
  }
  float bj[4];
  #pragma unroll
  for (int j = 0; j < 4; j++) bj[j] = bias[col0 + wn + j * 16 + l16];
  #pragma unroll
  for (int i = 0; i < 4; i++) {
    const int gm0 = row0 + wm + i * 16 + quad * 4;
    #pragma unroll
    for (int j = 0; j < 4; j++) {
      const int gc = col0 + wn + j * 16 + l16;
      #pragma unroll
      for (int r = 0; r < 4; r++)
        out[(size_t)(gm0 + r) * 1024 + gc] = acc[i][j][r] + bj[j];
    }
  }
}

// ---------------------------------------------------------------------------
extern "C" void kernel_launch(void* const* d_in, const int* in_sizes, int n_in,
                              void* d_out, int out_size, void* d_ws, size_t ws_size,
                              hipStream_t stream) {
  const float* x    = (const float*)d_in[0];
  const int*   mask = (const int*)d_in[1];   // bool mask as int32 (harness "integer -> int*")
  const float* Wqkv = (const float*)d_in[2];
  const float* Wout = (const float*)d_in[3];
  const float* bout = (const float*)d_in[4];
  float* out = (float*)d_out;
  char* ws = (char*)d_ws;
  // workspace layout (total ~150 MB)
  bf16*  xb     = (bf16*)(ws);                         // 16384*1024 bf16  (32 MB)
  bf16*  wt     = (bf16*)(ws + 33554432);              // 3072*1024 bf16   (6 MB)
  bf16*  qs     = (bf16*)(ws + 39845888);              // 16384*1024 bf16  (32 MB)
  bf16*  kv     = (bf16*)(ws + 73400320);              // 16384*2048 bf16  (64 MB)
  float* sumexp = (float*)(ws + 140509184);            // 4096 f32
  float* ctx    = (float*)(ws + 140525568);            // 64*64*64 f32 (1 MB)
  bf16*  m2t    = (bf16*)(ws + 141574144);             // 4*1024*1024 bf16 (8 MB)

  hipMemsetAsync(sumexp, 0, 16384 + 1048576, stream);  // zero sumexp + ctx
  k_cvt  <<<16384, 256, 0, stream>>>(x, xb, 4194304);
  k_trans<<<dim3(96, 32), 256, 0, stream>>>(Wqkv, wt);
  k_gemm1<<<dim3(24, 128), 256, 0, stream>>>(xb, wt, qs, kv);
  k_stats<<<dim3(16, 4, 4), 256, 0, stream>>>(kv, sumexp);
  k_ctx  <<<dim3(8, 16, 4), 256, 0, stream>>>(kv, mask, ctx);
  k_m2   <<<dim3(4, 16, 4), 256, 0, stream>>>(ctx, sumexp, Wout, m2t);
  k_gemm2<<<dim3(8, 128), 256, 0, stream>>>(qs, m2t, bout, out);
}

// Round 2
// 398.004 us; speedup vs baseline: 1.2030x; 1.2030x over previous
//
#include <hip/hip_runtime.h>
#include <math.h>

// ---------------------------------------------------------------------------
// LinearAttention, fully folded:
//   kv = x @ Wkv  (bf16 MFMA GEMM, 69 GF)
//   sumexp[b,d] = sum_n exp(k[b,n,d])           (softmax denom, pre-mask)
//   ctx[b,h,d,e] = sum_{n unmasked} exp(k)*v    (VALU outer product)
//   M2[b] = blockdiag_h(ctx/sumexp) @ Wout      -> M2t bf16
//   M3t[b] = M2t @ (s*Wq)^T                     (tiny MFMA GEMM)
//   out = x @ M3t^T + b_out                     (bf16 MFMA GEMM, 34 GF)
// B=4 T=4096 DIM=1024 H=16 Dh=64.
// ---------------------------------------------------------------------------

typedef __bf16 bf16;
typedef __attribute__((ext_vector_type(4))) float f32x4;
typedef __attribute__((ext_vector_type(8))) __bf16 bf16x8;
typedef __attribute__((ext_vector_type(4))) __bf16 bf16x4;

#define SCALE_ 0.125f   // 64^-0.5

__device__ __forceinline__ void g2l16(const void* g, void* l) {
  __builtin_amdgcn_global_load_lds((const __attribute__((address_space(1))) void*)g,
                                   (__attribute__((address_space(3))) void*)l, 16, 0, 0);
}

// ---- x (fp32) -> bf16, vectorized ----------------------------------------
__global__ __launch_bounds__(256) void k_cvt(const float* __restrict__ in,
                                             bf16* __restrict__ out, int n4) {
  int i = blockIdx.x * 256 + threadIdx.x;
  if (i >= n4) return;
  f32x4 v = ((const f32x4*)in)[i];
  bf16x4 o;
  o[0] = (bf16)v[0]; o[1] = (bf16)v[1]; o[2] = (bf16)v[2]; o[3] = (bf16)v[3];
  ((bf16x4*)out)[i] = o;
}

// ---- W_qkv[:,1024:3072] fp32 -> wt [2048][1024] bf16 (tiled transpose) ----
__global__ __launch_bounds__(256) void k_trans(const float* __restrict__ W,
                                               bf16* __restrict__ Wt) {
  __shared__ float t[32][33];
  int n0 = blockIdx.x * 32, k0 = blockIdx.y * 32;
  int tx = threadIdx.x & 31, ty = threadIdx.x >> 5;
  #pragma unroll
  for (int s = 0; s < 4; s++) {
    int k = ty + s * 8;
    t[k][tx] = W[(size_t)(k0 + k) * 3072 + 1024 + n0 + tx];
  }
  __syncthreads();
  #pragma unroll
  for (int s = 0; s < 4; s++) {
    int n = ty + s * 8;
    Wt[(size_t)(n0 + n) * 1024 + k0 + tx] = (bf16)t[tx][n];
  }
}

// ---- wqs[i][d] = scale * Wqkv[i][d]  (row-major copy of q-slice, bf16) ----
__global__ __launch_bounds__(256) void k_wq(const float* __restrict__ W,
                                            bf16* __restrict__ wqs) {
  int idx = blockIdx.x * 256 + threadIdx.x;     // 1024*256 total
  int i = idx >> 8, d4 = idx & 255;
  f32x4 v = *(const f32x4*)(W + (size_t)i * 3072 + d4 * 4);
  bf16x4 o;
  o[0] = (bf16)(v[0] * SCALE_); o[1] = (bf16)(v[1] * SCALE_);
  o[2] = (bf16)(v[2] * SCALE_); o[3] = (bf16)(v[3] * SCALE_);
  *(bf16x4*)(wqs + (size_t)i * 1024 + d4 * 4) = o;
}

// ---- GEMM1: xb[16384,1024] @ wt^T -> kv[16384,2048] bf16 (m97 structure) --
__global__ __launch_bounds__(256) void k_gemm1(const bf16* __restrict__ A,
                                               const bf16* __restrict__ Bt,
                                               bf16* __restrict__ kv) {
  __shared__ __align__(16) bf16 As[128 * 32];
  __shared__ __align__(16) bf16 Bs[128 * 32];
  const int tid = threadIdx.x;
  const int wave = tid >> 6, lane = tid & 63, l16 = lane & 15, quad = lane >> 4;
  const int wm = (wave >> 1) << 6, wn = (wave & 1) << 6;
  const int row0 = blockIdx.y << 7, col0 = blockIdx.x << 7;
  f32x4 acc[4][4] = {};
  for (int kt = 0; kt < 1024; kt += 32) {
    #pragma unroll
    for (int it = 0; it < 2; ++it) {
      const int cb = (wave * 2 + it) * 64;
      const int c = cb + lane;
      const int m = c >> 2, k8 = (c & 3) * 8;
      g2l16(A  + (size_t)(row0 + m) * 1024 + kt + k8, As + cb * 8);
      g2l16(Bt + (size_t)(col0 + m) * 1024 + kt + k8, Bs + cb * 8);
    }
    __syncthreads();
    bf16x8 af[4], bfr[4];
    #pragma unroll
    for (int i = 0; i < 4; i++) af[i]  = *(const bf16x8*)(As + (wm + i * 16 + l16) * 32 + quad * 8);
    #pragma unroll
    for (int j = 0; j < 4; j++) bfr[j] = *(const bf16x8*)(Bs + (wn + j * 16 + l16) * 32 + quad * 8);
    #pragma unroll
    for (int i = 0; i < 4; i++)
      #pragma unroll
      for (int j = 0; j < 4; j++)
        acc[i][j] = __builtin_amdgcn_mfma_f32_16x16x32_bf16(af[i], bfr[j], acc[i][j], 0, 0, 0);
    __syncthreads();
  }
  // C/D layout: col = lane&15, row = (lane>>4)*4 + reg  [m89-verified]
  #pragma unroll
  for (int i = 0; i < 4; i++) {
    const int gm0 = row0 + wm + i * 16 + quad * 4;
    #pragma unroll
    for (int j = 0; j < 4; j++) {
      const int gc = col0 + wn + j * 16 + l16;
      #pragma unroll
      for (int r = 0; r < 4; r++)
        kv[(size_t)(gm0 + r) * 2048 + gc] = (bf16)acc[i][j][r];
    }
  }
}

// ---- sumexp[b*1024+d] = sum_n exp(k[b,n,d]), bf16x8 column-group loads ----
__global__ __launch_bounds__(256) void k_stats(const bf16* __restrict__ kv,
                                               float* __restrict__ sumexp) {
  const int b = blockIdx.y, ns = blockIdx.x;              // grid (16,4)
  const int cg = threadIdx.x & 127, half = threadIdx.x >> 7;
  const int n0 = ns * 256 + half * 128;
  float s[8] = {};
  const bf16* p = kv + (size_t)(b * 4096 + n0) * 2048 + cg * 8;
  for (int i = 0; i < 128; i++) {
    bf16x8 t8 = *(const bf16x8*)(p + (size_t)i * 2048);
    #pragma unroll
    for (int j = 0; j < 8; j++) s[j] += __expf((float)t8[j]);
  }
  #pragma unroll
  for (int j = 0; j < 8; j++) atomicAdd(&sumexp[b * 1024 + cg * 8 + j], s[j]);
}

// ---- ctx[b,h,d,e] = sum_{n unmasked} exp(k[n,hd]) * v[n,he] ---------------
__global__ __launch_bounds__(256) void k_ctx(const bf16* __restrict__ kv,
                                             const int* __restrict__ mask,
                                             float* __restrict__ ctx) {
  __shared__ float Lk[64][68];   // +4 pad rotates row-start banks
  __shared__ float Lv[64][68];
  const int b = blockIdx.z, h = blockIdx.y, ns = blockIdx.x;
  const int tid = threadIdx.x, wave = tid >> 6, lane = tid & 63;
  const int d0 = (lane & 7) * 8, e0 = (lane >> 3) * 8;
  float acc[8][8] = {};
  const int nbase = ns * 512;
  for (int ch = 0; ch < 8; ++ch) {
    const int n0 = nbase + ch * 64;
    __syncthreads();
    #pragma unroll
    for (int it = 0; it < 2; ++it) {                 // k: exp + mask
      const int idx = it * 256 + tid;                // 0..511
      const int row = idx >> 3, g = idx & 7;
      const int gn = b * 4096 + n0 + row;
      const float m = mask[gn] ? 0.f : 1.f;
      bf16x8 t8 = *(const bf16x8*)(kv + (size_t)gn * 2048 + h * 64 + g * 8);
      f32x4 lo, hi;
      lo[0] = __expf((float)t8[0]) * m; lo[1] = __expf((float)t8[1]) * m;
      lo[2] = __expf((float)t8[2]) * m; lo[3] = __expf((float)t8[3]) * m;
      hi[0] = __expf((float)t8[4]) * m; hi[1] = __expf((float)t8[5]) * m;
      hi[2] = __expf((float)t8[6]) * m; hi[3] = __expf((float)t8[7]) * m;
      *(f32x4*)&Lk[row][g * 8] = lo;
      *(f32x4*)&Lk[row][g * 8 + 4] = hi;
    }
    #pragma unroll
    for (int it = 0; it < 2; ++it) {                 // v: plain convert
      const int idx = it * 256 + tid;
      const int row = idx >> 3, g = idx & 7;
      const int gn = b * 4096 + n0 + row;
      bf16x8 t8 = *(const bf16x8*)(kv + (size_t)gn * 2048 + 1024 + h * 64 + g * 8);
      f32x4 lo, hi;
      lo[0] = (float)t8[0]; lo[1] = (float)t8[1]; lo[2] = (float)t8[2]; lo[3] = (float)t8[3];
      hi[0] = (float)t8[4]; hi[1] = (float)t8[5]; hi[2] = (float)t8[6]; hi[3] = (float)t8[7];
      *(f32x4*)&Lv[row][g * 8] = lo;
      *(f32x4*)&Lv[row][g * 8 + 4] = hi;
    }
    __syncthreads();
    #pragma unroll 4
    for (int t = 0; t < 16; t++) {
      const int n = (wave << 4) + t;
      f32x4 ka = *(const f32x4*)&Lk[n][d0];
      f32x4 kb = *(const f32x4*)&Lk[n][d0 + 4];
      f32x4 va = *(const f32x4*)&Lv[n][e0];
      f32x4 vb = *(const f32x4*)&Lv[n][e0 + 4];
      float kk[8] = {ka[0], ka[1], ka[2], ka[3], kb[0], kb[1], kb[2], kb[3]};
      float vv[8] = {va[0], va[1], va[2], va[3], vb[0], vb[1], vb[2], vb[3]};
      #pragma unroll
      for (int a = 0; a < 8; a++)
        #pragma unroll
        for (int c = 0; c < 8; c++) acc[a][c] += kk[a] * vv[c];
    }
  }
  __syncthreads();
  float* r0 = &Lk[0][0];
  float* r1 = &Lv[0][0];
  if (wave < 2) {
    float* r = wave ? r1 : r0;
    #pragma unroll
    for (int a = 0; a < 8; a++)
      #pragma unroll
      for (int c = 0; c < 8; c++) r[(d0 + a) * 64 + e0 + c] = acc[a][c];
  }
  __syncthreads();
  if (wave >= 2) {
    float* r = (wave == 3) ? r1 : r0;
    #pragma unroll
    for (int a = 0; a < 8; a++)
      #pragma unroll
      for (int c = 0; c < 8; c++) r[(d0 + a) * 64 + e0 + c] += acc[a][c];
  }
  __syncthreads();
  float* cbase = ctx + ((size_t)(b * 16 + h) << 12);
  for (int i = tid; i < 4096; i += 256) atomicAdd(cbase + i, r0[i] + r1[i]);
}

// ---- M2t[b][j][h*64+d] = (1/sumexp[b,hd]) * sum_e ctx[b,h,d,e]*Wout[he][j] -
__global__ __launch_bounds__(256) void k_m2(const float* __restrict__ ctx,
                                            const float* __restrict__ sumexp,
                                            const float* __restrict__ Wout,
                                            bf16* __restrict__ M2t) {
  __shared__ float Lc[64][64];
  __shared__ float Linv[64];
  const int b = blockIdx.z, h = blockIdx.y, jt = blockIdx.x;
  const int tid = threadIdx.x, dg = tid >> 6, jl = tid & 63;
  const float* cbase = ctx + ((size_t)(b * 16 + h) << 12);
  for (int i = tid; i < 4096; i += 256) (&Lc[0][0])[i] = cbase[i];
  if (tid < 64) Linv[tid] = 1.f / sumexp[b * 1024 + h * 64 + tid];
  __syncthreads();
  float acc[4][16] = {};
  const int j0 = jt * 256 + jl;
  for (int e = 0; e < 64; e++) {
    const float* wrow = Wout + (size_t)(h * 64 + e) * 1024 + j0;
    float w0 = wrow[0], w1 = wrow[64], w2 = wrow[128], w3 = wrow[192];
    #pragma unroll
    for (int dd = 0; dd < 16; dd++) {
      float c = Lc[dg * 16 + dd][e];  // wave-uniform -> LDS broadcast
      acc[0][dd] += c * w0; acc[1][dd] += c * w1;
      acc[2][dd] += c * w2; acc[3][dd] += c * w3;
    }
  }
  #pragma unroll
  for (int jj = 0; jj < 4; jj++) {
    const size_t jrow = ((size_t)b << 20) + (size_t)(jt * 256 + jl + jj * 64) * 1024 + h * 64 + dg * 16;
    #pragma unroll
    for (int dd = 0; dd < 16; dd++)
      M2t[jrow + dd] = (bf16)(acc[jj][dd] * Linv[dg * 16 + dd]);
  }
}

// ---- M3t[b] = M2t[b] @ wqs^T, bf16 out (m97 structure, M=N=K=1024) --------
__global__ __launch_bounds__(256) void k_m3(const bf16* __restrict__ M2t,
                                            const bf16* __restrict__ wqs,
                                            bf16* __restrict__ M3t) {
  __shared__ __align__(16) bf16 As[128 * 32];
  __shared__ __align__(16) bf16 Bs[128 * 32];
  const int tid = threadIdx.x;
  const int wave = tid >> 6, lane = tid & 63, l16 = lane & 15, quad = lane >> 4;
  const int wm = (wave >> 1) << 6, wn = (wave & 1) << 6;
  const int row0 = blockIdx.y << 7, col0 = blockIdx.x << 7;
  const bf16* A  = M2t + ((size_t)blockIdx.z << 20);
  bf16*       C  = M3t + ((size_t)blockIdx.z << 20);
  f32x4 acc[4][4] = {};
  for (int kt = 0; kt < 1024; kt += 32) {
    #pragma unroll
    for (int it = 0; it < 2; ++it) {
      const int cb = (wave * 2 + it) * 64;
      const int c = cb + lane;
      const int m = c >> 2, k8 = (c & 3) * 8;
      g2l16(A   + (size_t)(row0 + m) * 1024 + kt + k8, As + cb * 8);
      g2l16(wqs + (size_t)(col0 + m) * 1024 + kt + k8, Bs + cb * 8);
    }
    __syncthreads();
    bf16x8 af[4], bfr[4];
    #pragma unroll
    for (int i = 0; i < 4; i++) af[i]  = *(const bf16x8*)(As + (wm + i * 16 + l16) * 32 + quad * 8);
    #pragma unroll
    for (int j = 0; j < 4; j++) bfr[j] = *(const bf16x8*)(Bs + (wn + j * 16 + l16) * 32 + quad * 8);
    #pragma unroll
    for (int i = 0; i < 4; i++)
      #pragma unroll
      for (int j = 0; j < 4; j++)
        acc[i][j] = __builtin_amdgcn_mfma_f32_16x16x32_bf16(af[i], bfr[j], acc[i][j], 0, 0, 0);
    __syncthreads();
  }
  #pragma unroll
  for (int i = 0; i < 4; i++) {
    const int gm0 = row0 + wm + i * 16 + quad * 4;
    #pragma unroll
    for (int j = 0; j < 4; j++) {
      const int gc = col0 + wn + j * 16 + l16;
      #pragma unroll
      for (int r = 0; r < 4; r++)
        C[(size_t)(gm0 + r) * 1024 + gc] = (bf16)acc[i][j][r];
    }
  }
}

// ---- GEMM2: out[b] = xb[b] @ M3t[b]^T + b_out, fp32 out -------------------
__global__ __launch_bounds__(256) void k_gemm2(const bf16* __restrict__ A,
                                               const bf16* __restrict__ M3t,
                                               const float* __restrict__ bias,
                                               float* __restrict__ out) {
  __shared__ __align__(16) bf16 As[128 * 32];
  __shared__ __align__(16) bf16 Bs[128 * 32];
  const int tid = threadIdx.x;
  const int wave = tid >> 6, lane = tid & 63, l16 = lane & 15, quad = lane >> 4;
  const int wm = (wave >> 1) << 6, wn = (wave & 1) << 6;
  const int row0 = blockIdx.y << 7, col0 = blockIdx.x << 7;
  const bf16* Bt = M3t + ((size_t)(row0 >> 12) << 20);  // per-batch M3
  f32x4 acc[4][4] = {};
  for (int kt = 0; kt < 1024; kt += 32) {
    #pragma unroll
    for (int it = 0; it < 2; ++it) {
      const int cb = (wave * 2 + it) * 64;
      const int c = cb + lane;
      const int m = c >> 2, k8 = (c & 3) * 8;
      g2l16(A  + (size_t)(row0 + m) * 1024 + kt + k8, As + cb * 8);
      g2l16(Bt + (size_t)(col0 + m) * 1024 + kt + k8, Bs + cb * 8);
    }
    __syncthreads();
    bf16x8 af[4], bfr[4];
    #pragma unroll
    for (int i = 0; i < 4; i++) af[i]  = *(const bf16x8*)(As + (wm + i * 16 + l16) * 32 + quad * 8);
    #pragma unroll
    for (int j = 0; j < 4; j++) bfr[j] = *(const bf16x8*)(Bs + (wn + j * 16 + l16) * 32 + quad * 8);
    #pragma unroll
    for (int i = 0; i < 4; i++)
      #pragma unroll
      for (int j = 0; j < 4; j++)
        acc[i][j] = __builtin_amdgcn_mfma_f32_16x16x32_bf16(af[i], bfr[j], acc[i][j], 0, 0, 0);
    __syncthreads();
  }
  float bj[4];
  #pragma unroll
  for (int j = 0; j < 4; j++) bj[j] = bias[col0 + wn + j * 16 + l16];
  #pragma unroll
  for (int i = 0; i < 4; i++) {
    const int gm0 = row0 + wm + i * 16 + quad * 4;
    #pragma unroll
    for (int j = 0; j < 4; j++) {
      const int gc = col0 + wn + j * 16 + l16;
      #pragma unroll
      for (int r = 0; r < 4; r++)
        out[(size_t)(gm0 + r) * 1024 + gc] = acc[i][j][r] + bj[j];
    }
  }
}

// ---------------------------------------------------------------------------
extern "C" void kernel_launch(void* const* d_in, const int* in_sizes, int n_in,
                              void* d_out, int out_size, void* d_ws, size_t ws_size,
                              hipStream_t stream) {
  const float* x    = (const float*)d_in[0];
  const int*   mask = (const int*)d_in[1];
  const float* Wqkv = (const float*)d_in[2];
  const float* Wout = (const float*)d_in[3];
  const float* bout = (const float*)d_in[4];
  float* out = (float*)d_out;
  char* ws = (char*)d_ws;
  // workspace layout (~119 MB)
  bf16*  xb     = (bf16*)(ws);                   // 16384*1024 bf16 (32 MB)
  bf16*  wt     = (bf16*)(ws + 33554432);        // 2048*1024 bf16  (4 MB)
  bf16*  wqs    = (bf16*)(ws + 37748736);        // 1024*1024 bf16  (2 MB)
  bf16*  kv     = (bf16*)(ws + 39845888);        // 16384*2048 bf16 (64 MB)
  float* sumexp = (float*)(ws + 106954752);      // 4096 f32 (16 KB)
  float* ctx    = (float*)(ws + 106971136);      // 4*16*64*64 f32 (1 MB)
  bf16*  m2t    = (bf16*)(ws + 108019712);       // 4*1024*1024 bf16 (8 MB)
  bf16*  m3t    = (bf16*)(ws + 116408320);       // 4*1024*1024 bf16 (8 MB)

  hipMemsetAsync(sumexp, 0, 16384 + 1048576, stream);   // sumexp + ctx
  k_cvt  <<<16384, 256, 0, stream>>>(x, xb, 4194304);
  k_trans<<<dim3(64, 32), 256, 0, stream>>>(Wqkv, wt);
  k_wq   <<<1024, 256, 0, stream>>>(Wqkv, wqs);
  k_gemm1<<<dim3(16, 128), 256, 0, stream>>>(xb, wt, kv);
  k_stats<<<dim3(16, 4), 256, 0, stream>>>(kv, sumexp);
  k_ctx  <<<dim3(8, 16, 4), 256, 0, stream>>>(kv, mask, ctx);
  k_m2   <<<dim3(4, 16, 4), 256, 0, stream>>>(ctx, sumexp, Wout, m2t);
  k_m3   <<<dim3(8, 8, 4), 256, 0, stream>>>(m2t, wqs, m3t);
  k_gemm2<<<dim3(8, 128), 256, 0, stream>>>(xb, m3t, bout, out);
}

// Round 6
// 349.186 us; speedup vs baseline: 1.3712x; 1.1398x over previous
//
#include <hip/hip_runtime.h>
#include <math.h>

// ---------------------------------------------------------------------------
// LinearAttention, folded. Plain dispatches only (no cooperative launch).
// Prep stage = round-2-verified separate kernels (bisecting the r3/r5 abort:
// fused k_prep was the first-launched novelty; reverted here).
//   cvt/trans/wq: x->bf16, Wkv^T->bf16, Wq*scale->bf16
//   gemm1: kv = x @ Wkv  (bf16 MFMA, XCD-swizzled)
//   ctx:   ctx[b,h,d,e] = sum_n_unmasked exp(k)*v ; sumexp folded (pre-mask)
//   m2:    M2t[b] = (blockdiag(ctx)/sumexp @ Wout)^T  bf16
//   m3:    M3t[b] = M2t[b] @ (s*Wq)^T                 bf16
//   gemm2: out = x @ M3t^T + b_out (fp32, XCD-swizzled)
// B=4 T=4096 DIM=1024 H=16 Dh=64.
// ---------------------------------------------------------------------------

typedef __bf16 bf16;
typedef __attribute__((ext_vector_type(4))) float f32x4;
typedef __attribute__((ext_vector_type(8))) __bf16 bf16x8;
typedef __attribute__((ext_vector_type(4))) __bf16 bf16x4;

#define SCALE_ 0.125f   // 64^-0.5

__device__ __forceinline__ void g2l16(const void* g, void* l) {
  __builtin_amdgcn_global_load_lds((const __attribute__((address_space(1))) void*)g,
                                   (__attribute__((address_space(3))) void*)l, 16, 0, 0);
}

// ---- x (fp32) -> bf16, vectorized (round-2 verified) ----------------------
__global__ __launch_bounds__(256) void k_cvt(const float* __restrict__ in,
                                             bf16* __restrict__ out, int n4) {
  int i = blockIdx.x * 256 + threadIdx.x;
  if (i >= n4) return;
  f32x4 v = ((const f32x4*)in)[i];
  bf16x4 o;
  o[0] = (bf16)v[0]; o[1] = (bf16)v[1]; o[2] = (bf16)v[2]; o[3] = (bf16)v[3];
  ((bf16x4*)out)[i] = o;
}

// ---- W_qkv[:,1024:3072] fp32 -> wt [2048][1024] bf16 (round-2 verified) ---
__global__ __launch_bounds__(256) void k_trans(const float* __restrict__ W,
                                               bf16* __restrict__ Wt) {
  __shared__ float t[32][33];
  int n0 = blockIdx.x * 32, k0 = blockIdx.y * 32;
  int tx = threadIdx.x & 31, ty = threadIdx.x >> 5;
  #pragma unroll
  for (int s = 0; s < 4; s++) {
    int k = ty + s * 8;
    t[k][tx] = W[(size_t)(k0 + k) * 3072 + 1024 + n0 + tx];
  }
  __syncthreads();
  #pragma unroll
  for (int s = 0; s < 4; s++) {
    int n = ty + s * 8;
    Wt[(size_t)(n0 + n) * 1024 + k0 + tx] = (bf16)t[tx][n];
  }
}

// ---- wqs[i][d] = scale * Wqkv[i][d] (round-2 verified) --------------------
__global__ __launch_bounds__(256) void k_wq(const float* __restrict__ W,
                                            bf16* __restrict__ wqs) {
  int idx = blockIdx.x * 256 + threadIdx.x;     // 1024*256 total
  int i = idx >> 8, d4 = idx & 255;
  f32x4 v = *(const f32x4*)(W + (size_t)i * 3072 + d4 * 4);
  bf16x4 o;
  o[0] = (bf16)(v[0] * SCALE_); o[1] = (bf16)(v[1] * SCALE_);
  o[2] = (bf16)(v[2] * SCALE_); o[3] = (bf16)(v[3] * SCALE_);
  *(bf16x4*)(wqs + (size_t)i * 1024 + d4 * 4) = o;
}

// ---- GEMM1: xb[16384,1024] @ wt^T -> kv[16384,2048] bf16, XCD-swizzled ----
__global__ __launch_bounds__(256) void k_gemm1(const bf16* __restrict__ A,
                                               const bf16* __restrict__ Bt,
                                               bf16* __restrict__ kv) {
  __shared__ __align__(16) bf16 As[128 * 32];
  __shared__ __align__(16) bf16 Bs[128 * 32];
  const int tid = threadIdx.x;
  const int wave = tid >> 6, lane = tid & 63, l16 = lane & 15, quad = lane >> 4;
  const int wm = (wave >> 1) << 6, wn = (wave & 1) << 6;
  // XCD swizzle: id%8 = XCD; each XCD owns a contiguous 16-row-tile band
  const int f = blockIdx.x, xcd = f & 7, w = f >> 3;
  const int row0 = (xcd * 16 + (w >> 4)) << 7;   // 128 row tiles
  const int col0 = (w & 15) << 7;                // 16 col tiles
  f32x4 acc[4][4] = {};
  for (int kt = 0; kt < 1024; kt += 32) {
    #pragma unroll
    for (int it = 0; it < 2; ++it) {
      const int cb = (wave * 2 + it) * 64;
      const int c = cb + lane;
      const int m = c >> 2, k8 = (c & 3) * 8;
      g2l16(A  + (size_t)(row0 + m) * 1024 + kt + k8, As + cb * 8);
      g2l16(Bt + (size_t)(col0 + m) * 1024 + kt + k8, Bs + cb * 8);
    }
    __syncthreads();
    bf16x8 af[4], bfr[4];
    #pragma unroll
    for (int i = 0; i < 4; i++) af[i]  = *(const bf16x8*)(As + (wm + i * 16 + l16) * 32 + quad * 8);
    #pragma unroll
    for (int j = 0; j < 4; j++) bfr[j] = *(const bf16x8*)(Bs + (wn + j * 16 + l16) * 32 + quad * 8);
    #pragma unroll
    for (int i = 0; i < 4; i++)
      #pragma unroll
      for (int j = 0; j < 4; j++)
        acc[i][j] = __builtin_amdgcn_mfma_f32_16x16x32_bf16(af[i], bfr[j], acc[i][j], 0, 0, 0);
    __syncthreads();
  }
  #pragma unroll
  for (int i = 0; i < 4; i++) {
    const int gm0 = row0 + wm + i * 16 + quad * 4;
    #pragma unroll
    for (int j = 0; j < 4; j++) {
      const int gc = col0 + wn + j * 16 + l16;
      #pragma unroll
      for (int r = 0; r < 4; r++)
        kv[(size_t)(gm0 + r) * 2048 + gc] = (bf16)acc[i][j][r];
    }
  }
}

// ---- ctx[b,h,d,e] = sum_{n unmasked} exp(k[n,hd]) * v[n,he]; sumexp folded -
__global__ __launch_bounds__(256) void k_ctx(const bf16* __restrict__ kv,
                                             const int* __restrict__ mask,
                                             float* __restrict__ sumexp,
                                             float* __restrict__ ctx) {
  __shared__ float Lk[64][68];
  __shared__ float Lv[64][68];
  __shared__ float Sst[64][33];
  const int blk = blockIdx.x, tid = threadIdx.x;
  const int wave = tid >> 6, lane = tid & 63;
  const int ns = blk & 7, h = (blk >> 3) & 15, b = blk >> 7;
  const int d0 = (lane & 7) * 8, e0 = (lane >> 3) * 8;
  const int g = tid & 7;                 // col-group, constant per thread
  float acc[8][8] = {};
  float sum8[8] = {};
  const int nbase = ns * 512;
  for (int ch = 0; ch < 8; ++ch) {
    const int n0 = nbase + ch * 64;
    __syncthreads();
    #pragma unroll
    for (int it = 0; it < 2; ++it) {               // k: exp, sum pre-mask, mask
      const int idx = it * 256 + tid;
      const int row = idx >> 3;
      const int gn = b * 4096 + n0 + row;
      const float m = mask[gn] ? 0.f : 1.f;
      bf16x8 t8 = *(const bf16x8*)(kv + (size_t)gn * 2048 + h * 64 + g * 8);
      float e[8];
      #pragma unroll
      for (int j = 0; j < 8; j++) { e[j] = __expf((float)t8[j]); sum8[j] += e[j]; }
      f32x4 lo, hi;
      lo[0] = e[0] * m; lo[1] = e[1] * m; lo[2] = e[2] * m; lo[3] = e[3] * m;
      hi[0] = e[4] * m; hi[1] = e[5] * m; hi[2] = e[6] * m; hi[3] = e[7] * m;
      *(f32x4*)&Lk[row][g * 8] = lo;
      *(f32x4*)&Lk[row][g * 8 + 4] = hi;
    }
    #pragma unroll
    for (int it = 0; it < 2; ++it) {               // v: plain convert
      const int idx = it * 256 + tid;
      const int row = idx >> 3;
      const int gn = b * 4096 + n0 + row;
      bf16x8 t8 = *(const bf16x8*)(kv + (size_t)gn * 2048 + 1024 + h * 64 + g * 8);
      f32x4 lo, hi;
      lo[0] = (float)t8[0]; lo[1] = (float)t8[1]; lo[2] = (float)t8[2]; lo[3] = (float)t8[3];
      hi[0] = (float)t8[4]; hi[1] = (float)t8[5]; hi[2] = (float)t8[6]; hi[3] = (float)t8[7];
      *(f32x4*)&Lv[row][g * 8] = lo;
      *(f32x4*)&Lv[row][g * 8 + 4] = hi;
    }
    __syncthreads();
    #pragma unroll 4
    for (int t = 0; t < 16; t++) {
      const int n = (wave << 4) + t;
      f32x4 ka = *(const f32x4*)&Lk[n][d0];
      f32x4 kb = *(const f32x4*)&Lk[n][d0 + 4];
      f32x4 va = *(const f32x4*)&Lv[n][e0];
      f32x4 vb = *(const f32x4*)&Lv[n][e0 + 4];
      float kk[8] = {ka[0], ka[1], ka[2], ka[3], kb[0], kb[1], kb[2], kb[3]};
      float vv[8] = {va[0], va[1], va[2], va[3], vb[0], vb[1], vb[2], vb[3]};
      #pragma unroll
      for (int a = 0; a < 8; a++)
        #pragma unroll
        for (int c = 0; c < 8; c++) acc[a][c] += kk[a] * vv[c];
    }
  }
  __syncthreads();
  float* r0 = &Lk[0][0];                           // reuse, stride 64
  float* r1 = &Lv[0][0];
  if (wave < 2) {
    float* r = wave ? r1 : r0;
    #pragma unroll
    for (int a = 0; a < 8; a++)
      #pragma unroll
      for (int c = 0; c < 8; c++) r[(d0 + a) * 64 + e0 + c] = acc[a][c];
  }
  {  // sumexp partials: Sst[col][rowgrp]
    const int rg = tid >> 3;
    #pragma unroll
    for (int j = 0; j < 8; j++) Sst[g * 8 + j][rg] = sum8[j];
  }
  __syncthreads();
  if (wave >= 2) {
    float* r = (wave == 3) ? r1 : r0;
    #pragma unroll
    for (int a = 0; a < 8; a++)
      #pragma unroll
      for (int c = 0; c < 8; c++) r[(d0 + a) * 64 + e0 + c] += acc[a][c];
  } else if (tid < 64) {                           // reduce sumexp col
    float s = 0.f;
    #pragma unroll 8
    for (int rg = 0; rg < 32; rg++) s += Sst[tid][rg];
    atomicAdd(&sumexp[b * 1024 + h * 64 + tid], s);
  }
  __syncthreads();
  float* cbase = ctx + ((size_t)(b * 16 + h) << 12);
  for (int i = tid; i < 4096; i += 256) atomicAdd(cbase + i, r0[i] + r1[i]);
}

// ---- M2t[b][j][h*64+d] = (1/sumexp[b,hd]) * sum_e ctx[b,h,d,e]*Wout[he][j] -
__global__ __launch_bounds__(256) void k_m2(const float* __restrict__ ctx,
                                            const float* __restrict__ sumexp,
                                            const float* __restrict__ Wout,
                                            bf16* __restrict__ M2t) {
  __shared__ float Lc[64][64];
  __shared__ float Linv[64];
  const int b = blockIdx.z, h = blockIdx.y, jt = blockIdx.x;
  const int tid = threadIdx.x, dg = tid >> 6, jl = tid & 63;
  const float* cbase = ctx + ((size_t)(b * 16 + h) << 12);
  for (int i = tid; i < 4096; i += 256) (&Lc[0][0])[i] = cbase[i];
  if (tid < 64) Linv[tid] = 1.f / sumexp[b * 1024 + h * 64 + tid];
  __syncthreads();
  float acc[4][16] = {};
  const int j0 = jt * 256 + jl;
  for (int e = 0; e < 64; e++) {
    const float* wrow = Wout + (size_t)(h * 64 + e) * 1024 + j0;
    float w0 = wrow[0], w1 = wrow[64], w2 = wrow[128], w3 = wrow[192];
    #pragma unroll
    for (int dd = 0; dd < 16; dd++) {
      float c = Lc[dg * 16 + dd][e];  // wave-uniform -> LDS broadcast
      acc[0][dd] += c * w0; acc[1][dd] += c * w1;
      acc[2][dd] += c * w2; acc[3][dd] += c * w3;
    }
  }
  #pragma unroll
  for (int jj = 0; jj < 4; jj++) {
    const size_t jrow = ((size_t)b << 20) + (size_t)(jt * 256 + jl + jj * 64) * 1024 + h * 64 + dg * 16;
    #pragma unroll
    for (int dd = 0; dd < 16; dd++)
      M2t[jrow + dd] = (bf16)(acc[jj][dd] * Linv[dg * 16 + dd]);
  }
}

// ---- M3t[b] = M2t[b] @ wqs^T, bf16 out (m97 structure, M=N=K=1024) --------
__global__ __launch_bounds__(256) void k_m3(const bf16* __restrict__ M2t,
                                            const bf16* __restrict__ wqs,
                                            bf16* __restrict__ M3t) {
  __shared__ __align__(16) bf16 As[128 * 32];
  __shared__ __align__(16) bf16 Bs[128 * 32];
  const int tid = threadIdx.x;
  const int wave = tid >> 6, lane = tid & 63, l16 = lane & 15, quad = lane >> 4;
  const int wm = (wave >> 1) << 6, wn = (wave & 1) << 6;
  const int row0 = blockIdx.y << 7, col0 = blockIdx.x << 7;
  const bf16* A  = M2t + ((size_t)blockIdx.z << 20);
  bf16*       C  = M3t + ((size_t)blockIdx.z << 20);
  f32x4 acc[4][4] = {};
  for (int kt = 0; kt < 1024; kt += 32) {
    #pragma unroll
    for (int it = 0; it < 2; ++it) {
      const int cb = (wave * 2 + it) * 64;
      const int c = cb + lane;
      const int m = c >> 2, k8 = (c & 3) * 8;
      g2l16(A   + (size_t)(row0 + m) * 1024 + kt + k8, As + cb * 8);
      g2l16(wqs + (size_t)(col0 + m) * 1024 + kt + k8, Bs + cb * 8);
    }
    __syncthreads();
    bf16x8 af[4], bfr[4];
    #pragma unroll
    for (int i = 0; i < 4; i++) af[i]  = *(const bf16x8*)(As + (wm + i * 16 + l16) * 32 + quad * 8);
    #pragma unroll
    for (int j = 0; j < 4; j++) bfr[j] = *(const bf16x8*)(Bs + (wn + j * 16 + l16) * 32 + quad * 8);
    #pragma unroll
    for (int i = 0; i < 4; i++)
      #pragma unroll
      for (int j = 0; j < 4; j++)
        acc[i][j] = __builtin_amdgcn_mfma_f32_16x16x32_bf16(af[i], bfr[j], acc[i][j], 0, 0, 0);
    __syncthreads();
  }
  #pragma unroll
  for (int i = 0; i < 4; i++) {
    const int gm0 = row0 + wm + i * 16 + quad * 4;
    #pragma unroll
    for (int j = 0; j < 4; j++) {
      const int gc = col0 + wn + j * 16 + l16;
      #pragma unroll
      for (int r = 0; r < 4; r++)
        C[(size_t)(gm0 + r) * 1024 + gc] = (bf16)acc[i][j][r];
    }
  }
}

// ---- GEMM2: out[b] = xb[b] @ M3t[b]^T + b_out, fp32, XCD-swizzled ---------
__global__ __launch_bounds__(256) void k_gemm2(const bf16* __restrict__ A,
                                               const bf16* __restrict__ M3t,
                                               const float* __restrict__ bias,
                                               float* __restrict__ out) {
  __shared__ __align__(16) bf16 As[128 * 32];
  __shared__ __align__(16) bf16 Bs[128 * 32];
  const int tid = threadIdx.x;
  const int wave = tid >> 6, lane = tid & 63, l16 = lane & 15, quad = lane >> 4;
  const int wm = (wave >> 1) << 6, wn = (wave & 1) << 6;
  const int f = blockIdx.x, xcd = f & 7, w = f >> 3;
  const int row0 = (xcd * 16 + (w >> 3)) << 7;   // 128 row tiles
  const int col0 = (w & 7) << 7;                 // 8 col tiles
  const bf16* Bt = M3t + ((size_t)(row0 >> 12) << 20);
  f32x4 acc[4][4] = {};
  for (int kt = 0; kt < 1024; kt += 32) {
    #pragma unroll
    for (int it = 0; it < 2; ++it) {
      const int cb = (wave * 2 + it) * 64;
      const int c = cb + lane;
      const int m = c >> 2, k8 = (c & 3) * 8;
      g2l16(A  + (size_t)(row0 + m) * 1024 + kt + k8, As + cb * 8);
      g2l16(Bt + (size_t)(col0 + m) * 1024 + kt + k8, Bs + cb * 8);
    }
    __syncthreads();
    bf16x8 af[4], bfr[4];
    #pragma unroll
    for (int i = 0; i < 4; i++) af[i]  = *(const bf16x8*)(As + (wm + i * 16 + l16) * 32 + quad * 8);
    #pragma unroll
    for (int j = 0; j < 4; j++) bfr[j] = *(const bf16x8*)(Bs + (wn + j * 16 + l16) * 32 + quad * 8);
    #pragma unroll
    for (int i = 0; i < 4; i++)
      #pragma unroll
      for (int j = 0; j < 4; j++)
        acc[i][j] = __builtin_amdgcn_mfma_f32_16x16x32_bf16(af[i], bfr[j], acc[i][j], 0, 0, 0);
    __syncthreads();
  }
  float bj[4];
  #pragma unroll
  for (int j = 0; j < 4; j++) bj[j] = bias[col0 + wn + j * 16 + l16];
  #pragma unroll
  for (int i = 0; i < 4; i++) {
    const int gm0 = row0 + wm + i * 16 + quad * 4;
    #pragma unroll
    for (int j = 0; j < 4; j++) {
      const int gc = col0 + wn + j * 16 + l16;
      #pragma unroll
      for (int r = 0; r < 4; r++)
        out[(size_t)(gm0 + r) * 1024 + gc] = acc[i][j][r] + bj[j];
    }
  }
}

// ---------------------------------------------------------------------------
extern "C" void kernel_launch(void* const* d_in, const int* in_sizes, int n_in,
                              void* d_out, int out_size, void* d_ws, size_t ws_size,
                              hipStream_t stream) {
  const float* x    = (const float*)d_in[0];
  const int*   mask = (const int*)d_in[1];
  const float* Wqkv = (const float*)d_in[2];
  const float* Wout = (const float*)d_in[3];
  const float* bout = (const float*)d_in[4];
  float* out = (float*)d_out;
  char* ws = (char*)d_ws;
  bf16*  xb     = (bf16*)(ws);                   // 16384*1024 bf16 (32 MB)
  bf16*  wt     = (bf16*)(ws + 33554432);        // 2048*1024 bf16  (4 MB)
  bf16*  wqs    = (bf16*)(ws + 37748736);        // 1024*1024 bf16  (2 MB)
  bf16*  kv     = (bf16*)(ws + 39845888);        // 16384*2048 bf16 (64 MB)
  float* sumexp = (float*)(ws + 106954752);      // 4096 f32 (16 KB)
  float* ctx    = (float*)(ws + 106971136);      // 4*16*64*64 f32 (1 MB)
  bf16*  m2t    = (bf16*)(ws + 108019712);       // 4*1024*1024 bf16 (8 MB)
  bf16*  m3t    = (bf16*)(ws + 116408320);       // 4*1024*1024 bf16 (8 MB)

  hipMemsetAsync(sumexp, 0, 16384 + 1048576, stream);   // sumexp + ctx
  k_cvt  <<<16384, 256, 0, stream>>>(x, xb, 4194304);
  k_trans<<<dim3(64, 32), 256, 0, stream>>>(Wqkv, wt);
  k_wq   <<<1024, 256, 0, stream>>>(Wqkv, wqs);
  k_gemm1<<<2048, 256, 0, stream>>>(xb, wt, kv);
  k_ctx  <<<512, 256, 0, stream>>>(kv, mask, sumexp, ctx);
  k_m2   <<<dim3(4, 16, 4), 256, 0, stream>>>(ctx, sumexp, Wout, m2t);
  k_m3   <<<dim3(8, 8, 4), 256, 0, stream>>>(m2t, wqs, m3t);
  k_gemm2<<<1024, 256, 0, stream>>>(xb, m3t, bout, out);
}